// Round 1
// baseline (1823.873 us; speedup 1.0000x reference)
//
#include <hip/hip_runtime.h>
#include <hip/hip_bf16.h>

#define H 1024
#define B_TOK 16384

typedef __attribute__((ext_vector_type(8))) short s16x8;
typedef __attribute__((ext_vector_type(4))) float f32x4;

__device__ __forceinline__ short f2bf(float f) {
  __hip_bfloat16 h = __float2bfloat16(f);
  return __builtin_bit_cast(short, h);
}

__device__ __forceinline__ void load_lds16(const short* g, short* l) {
  __builtin_amdgcn_global_load_lds((const __attribute__((address_space(1))) void*)g,
                                   (__attribute__((address_space(3))) void*)l,
                                   16, 0, 0);
}

// ---------------- convert x -> bf16 ----------------
__global__ void cvt_x_k(const float* __restrict__ x, short* __restrict__ xb) {
  const size_t i = ((size_t)blockIdx.x * blockDim.x + threadIdx.x) * 8;
  const float4 a = *(const float4*)(x + i);
  const float4 b = *(const float4*)(x + i + 4);
  s16x8 v;
  v[0] = f2bf(a.x); v[1] = f2bf(a.y); v[2] = f2bf(a.z); v[3] = f2bf(a.w);
  v[4] = f2bf(b.x); v[5] = f2bf(b.y); v[6] = f2bf(b.z); v[7] = f2bf(b.w);
  *(s16x8*)(xb + i) = v;
}

// ---------------- transpose+convert all weights: W[K][N] f32 -> Wt[N][K] bf16 ----------------
__global__ void transpose_k(const float* __restrict__ sw1, const float* __restrict__ rw1,
                            const float* __restrict__ sw2, const float* __restrict__ rw2,
                            short* __restrict__ w1t, short* __restrict__ w2t) {
  __shared__ float tile[64][65];
  const int z = blockIdx.z;
  const float* src;
  short* dst;
  if (z < 8) {
    src = (z < 2) ? sw1 + (size_t)z * H * H : rw1 + (size_t)(z - 2) * H * H;
    dst = w1t + (size_t)z * H * H;
  } else {
    const int e = z - 8;
    src = (e < 2) ? sw2 + (size_t)e * H * H : rw2 + (size_t)(e - 2) * H * H;
    dst = w2t + (size_t)e * H * H;
  }
  const int k0 = blockIdx.y * 64, n0 = blockIdx.x * 64;
  const int t = threadIdx.x;
#pragma unroll
  for (int i = 0; i < 4; ++i) {
    const int kk = (t >> 4) + 16 * i;
    const int nn = (t & 15) * 4;
    const float4 v = *(const float4*)(src + (size_t)(k0 + kk) * H + n0 + nn);
    tile[nn + 0][kk] = v.x; tile[nn + 1][kk] = v.y;
    tile[nn + 2][kk] = v.z; tile[nn + 3][kk] = v.w;
  }
  __syncthreads();
  const int nn = t >> 2;
  const int kk = (t & 3) * 16;
  s16x8 o0, o1;
#pragma unroll
  for (int u = 0; u < 8; ++u) {
    o0[u] = f2bf(tile[nn][kk + u]);
    o1[u] = f2bf(tile[nn][kk + 8 + u]);
  }
  *(s16x8*)(dst + (size_t)(n0 + nn) * H + k0 + kk) = o0;
  *(s16x8*)(dst + (size_t)(n0 + nn) * H + k0 + kk + 8) = o1;
}

// ---------------- router: logits -> softmax -> top-2 -> per-expert weights ----------------
// wgt layout: [8][B_TOK]; experts 0,1 (shared) get 1.0, experts 2..7 get masked softmax wt.
__global__ void router_k(const float* __restrict__ x, const float* __restrict__ rw,
                         const float* __restrict__ rb, float* __restrict__ wgt) {
  const int lane = threadIdx.x & 63;
  const int b = blockIdx.x * 4 + (threadIdx.x >> 6);
  const float* xr = x + (size_t)b * H;
  float p[6] = {0.f, 0.f, 0.f, 0.f, 0.f, 0.f};
  for (int k = lane; k < H; k += 64) {
    const float xv = xr[k];
    const float* r = rw + k * 6;
#pragma unroll
    for (int e = 0; e < 6; ++e) p[e] += xv * r[e];
  }
#pragma unroll
  for (int e = 0; e < 6; ++e) {
    float v = p[e];
    for (int off = 32; off > 0; off >>= 1) v += __shfl_down(v, off);
    p[e] = v;
  }
  if (lane == 0) {
    float lg[6];
    float mx = -1e30f;
#pragma unroll
    for (int e = 0; e < 6; ++e) { lg[e] = p[e] + rb[e]; mx = fmaxf(mx, lg[e]); }
    float s = 0.f;
#pragma unroll
    for (int e = 0; e < 6; ++e) { lg[e] = __expf(lg[e] - mx); s += lg[e]; }
    const float inv = 1.f / s;
#pragma unroll
    for (int e = 0; e < 6; ++e) lg[e] *= inv;
    int i1 = 0;
#pragma unroll
    for (int e = 1; e < 6; ++e) if (lg[e] > lg[i1]) i1 = e;
    int i2 = (i1 == 0) ? 1 : 0;
#pragma unroll
    for (int e = 0; e < 6; ++e) if (e != i1 && lg[e] > lg[i2]) i2 = e;
    wgt[b] = 1.f;
    wgt[B_TOK + b] = 1.f;
#pragma unroll
    for (int e = 0; e < 6; ++e)
      wgt[(size_t)(2 + e) * B_TOK + b] = (e == i1 || e == i2) ? lg[e] : 0.f;
  }
}

// ---------------- GEMM core: C[128x128] += A[M,K] x Bt[N,K]^T, bf16 MFMA ----------------
// LDS chunks stored in exact MFMA fragment order: chunk = 64 lanes x 16B,
// lane l <-> element [tile*16 + (l&15)][k0 + (l>>4)*8 + j]  (works for A and Bt rows).
__device__ __forceinline__ void gemm_core(const short* __restrict__ A,
                                          const short* __restrict__ Bt,
                                          short* As, short* Bs,
                                          int m0, int n0, f32x4 acc[4][4]) {
  const int tid  = threadIdx.x;
  const int lane = tid & 63;
  const int w    = tid >> 6;
  const int q8   = (lane >> 4) * 8;
  const int r16  = lane & 15;
  const int wr   = w >> 1, wc = w & 1;

  for (int k0 = 0; k0 < H; k0 += 32) {
    __syncthreads();
#pragma unroll
    for (int i = 0; i < 4; ++i) {
      const int c = w * 4 + i;
      if (c < 8) {
        load_lds16(A + (size_t)(m0 + c * 16 + r16) * H + k0 + q8, As + c * 512);
      } else {
        const int nt = c - 8;
        load_lds16(Bt + (size_t)(n0 + nt * 16 + r16) * H + k0 + q8, Bs + nt * 512);
      }
    }
    __syncthreads();
    s16x8 af[4], bfv[4];
#pragma unroll
    for (int i = 0; i < 4; ++i) af[i]  = *(const s16x8*)(As + (wr * 4 + i) * 512 + lane * 8);
#pragma unroll
    for (int j = 0; j < 4; ++j) bfv[j] = *(const s16x8*)(Bs + (wc * 4 + j) * 512 + lane * 8);
#pragma unroll
    for (int i = 0; i < 4; ++i)
#pragma unroll
      for (int j = 0; j < 4; ++j)
        acc[i][j] = __builtin_amdgcn_mfma_f32_16x16x32_bf16(af[i], bfv[j], acc[i][j], 0, 0, 0);
  }
}

// GEMM1: hmid = tanh(x @ W1 + b1), bf16 out
__global__ __launch_bounds__(256) void gemm1_k(const short* __restrict__ A,
                                               const short* __restrict__ Bt,
                                               const float* __restrict__ bias,
                                               short* __restrict__ Out) {
  __shared__ __align__(16) short As[4096];
  __shared__ __align__(16) short Bs[4096];
  const int n0 = blockIdx.x * 128, m0 = blockIdx.y * 128;
  f32x4 acc[4][4];
#pragma unroll
  for (int i = 0; i < 4; ++i)
#pragma unroll
    for (int j = 0; j < 4; ++j) acc[i][j] = (f32x4){0.f, 0.f, 0.f, 0.f};
  gemm_core(A, Bt, As, Bs, m0, n0, acc);
  const int lane = threadIdx.x & 63, w = threadIdx.x >> 6;
  const int wr = w >> 1, wc = w & 1, q = lane >> 4, c16 = lane & 15;
  const int mb = m0 + wr * 64, nb = n0 + wc * 64;
#pragma unroll
  for (int j = 0; j < 4; ++j) {
    const int col = nb + j * 16 + c16;
    const float bv = bias[col];
#pragma unroll
    for (int i = 0; i < 4; ++i)
#pragma unroll
      for (int r = 0; r < 4; ++r) {
        const int row = mb + i * 16 + q * 4 + r;
        Out[(size_t)row * H + col] = f2bf(tanhf(acc[i][j][r] + bv));
      }
  }
}

// GEMM2: out (+)= wgt[row] * (hmid @ W2 + b2), fp32 out
__global__ __launch_bounds__(256) void gemm2_k(const short* __restrict__ A,
                                               const short* __restrict__ Bt,
                                               const float* __restrict__ bias,
                                               const float* __restrict__ wgt,
                                               float* __restrict__ Out, int accum) {
  __shared__ __align__(16) short As[4096];
  __shared__ __align__(16) short Bs[4096];
  const int n0 = blockIdx.x * 128, m0 = blockIdx.y * 128;
  f32x4 acc[4][4];
#pragma unroll
  for (int i = 0; i < 4; ++i)
#pragma unroll
    for (int j = 0; j < 4; ++j) acc[i][j] = (f32x4){0.f, 0.f, 0.f, 0.f};
  gemm_core(A, Bt, As, Bs, m0, n0, acc);
  const int lane = threadIdx.x & 63, w = threadIdx.x >> 6;
  const int wr = w >> 1, wc = w & 1, q = lane >> 4, c16 = lane & 15;
  const int mb = m0 + wr * 64, nb = n0 + wc * 64;
#pragma unroll
  for (int i = 0; i < 4; ++i) {
    float sc[4];
#pragma unroll
    for (int r = 0; r < 4; ++r) sc[r] = wgt[mb + i * 16 + q * 4 + r];
#pragma unroll
    for (int j = 0; j < 4; ++j) {
      const int col = nb + j * 16 + c16;
      const float bv = bias[col];
#pragma unroll
      for (int r = 0; r < 4; ++r) {
        const int row = mb + i * 16 + q * 4 + r;
        const size_t o = (size_t)row * H + col;
        const float v = (acc[i][j][r] + bv) * sc[r];
        Out[o] = accum ? Out[o] + v : v;
      }
    }
  }
}

extern "C" void kernel_launch(void* const* d_in, const int* in_sizes, int n_in,
                              void* d_out, int out_size, void* d_ws, size_t ws_size,
                              hipStream_t stream) {
  const float* x        = (const float*)d_in[0];
  const float* sw1      = (const float*)d_in[1];
  const float* sb1      = (const float*)d_in[2];
  const float* sw2      = (const float*)d_in[3];
  const float* sb2      = (const float*)d_in[4];
  const float* rw1      = (const float*)d_in[5];
  const float* rb1      = (const float*)d_in[6];
  const float* rw2      = (const float*)d_in[7];
  const float* rb2      = (const float*)d_in[8];
  const float* router_w = (const float*)d_in[9];
  const float* router_b = (const float*)d_in[10];
  float* out = (float*)d_out;

  char* ws = (char*)d_ws;
  short* xb  = (short*)(ws);                        // 16384*1024 bf16 = 32 MB
  short* hm  = (short*)(ws + (size_t)33554432);     // 32 MB
  short* w1t = (short*)(ws + (size_t)67108864);     // 8*1M bf16 = 16 MB
  short* w2t = (short*)(ws + (size_t)83886080);     // 16 MB
  float* wgt = (float*)(ws + (size_t)100663296);    // 8*16384 f32 = 0.5 MB

  cvt_x_k<<<8192, 256, 0, stream>>>(x, xb);
  transpose_k<<<dim3(16, 16, 16), 256, 0, stream>>>(sw1, rw1, sw2, rw2, w1t, w2t);
  router_k<<<4096, 256, 0, stream>>>(x, router_w, router_b, wgt);

  const dim3 g(8, 128);
  for (int e = 0; e < 8; ++e) {
    const float* b1 = (e < 2) ? sb1 + (size_t)e * H : rb1 + (size_t)(e - 2) * H;
    const float* b2 = (e < 2) ? sb2 + (size_t)e * H : rb2 + (size_t)(e - 2) * H;
    gemm1_k<<<g, 256, 0, stream>>>(xb, w1t + (size_t)e * H * H, b1, hm);
    gemm2_k<<<g, 256, 0, stream>>>(hm, w2t + (size_t)e * H * H, b2,
                                   wgt + (size_t)e * B_TOK, out, e == 0 ? 0 : 1);
  }
}

// Round 2
// 1504.158 us; speedup vs baseline: 1.2126x; 1.2126x over previous
//
#include <hip/hip_runtime.h>
#include <hip/hip_bf16.h>

#define H 1024
#define B_TOK 16384

typedef __attribute__((ext_vector_type(8))) short s16x8;
typedef __attribute__((ext_vector_type(4))) float f32x4;

__device__ __forceinline__ short f2bf(float f) {
  __hip_bfloat16 h = __float2bfloat16(f);
  return __builtin_bit_cast(short, h);
}
__device__ __forceinline__ float bf2f(short s) {
  __hip_bfloat16 h = __builtin_bit_cast(__hip_bfloat16, s);
  return __bfloat162float(h);
}

__device__ __forceinline__ void load_lds16(const short* g, short* l) {
  __builtin_amdgcn_global_load_lds((const __attribute__((address_space(1))) void*)g,
                                   (__attribute__((address_space(3))) void*)l,
                                   16, 0, 0);
}

// ---------------- convert x -> bf16 ----------------
__global__ void cvt_x_k(const float* __restrict__ x, short* __restrict__ xb) {
  const size_t i = ((size_t)blockIdx.x * blockDim.x + threadIdx.x) * 8;
  const float4 a = *(const float4*)(x + i);
  const float4 b = *(const float4*)(x + i + 4);
  s16x8 v;
  v[0] = f2bf(a.x); v[1] = f2bf(a.y); v[2] = f2bf(a.z); v[3] = f2bf(a.w);
  v[4] = f2bf(b.x); v[5] = f2bf(b.y); v[6] = f2bf(b.z); v[7] = f2bf(b.w);
  *(s16x8*)(xb + i) = v;
}

// ---------------- transpose+convert weights: W[K][N] f32 -> Wt[N][K] bf16 ----------------
__global__ void transpose_k(const float* __restrict__ sw1, const float* __restrict__ rw1,
                            const float* __restrict__ sw2, const float* __restrict__ rw2,
                            short* __restrict__ w1t, short* __restrict__ w2t) {
  __shared__ float tile[64][65];
  const int z = blockIdx.z;
  const float* src;
  short* dst;
  if (z < 8) {
    src = (z < 2) ? sw1 + (size_t)z * H * H : rw1 + (size_t)(z - 2) * H * H;
    dst = w1t + (size_t)z * H * H;
  } else {
    const int e = z - 8;
    src = (e < 2) ? sw2 + (size_t)e * H * H : rw2 + (size_t)(e - 2) * H * H;
    dst = w2t + (size_t)e * H * H;
  }
  const int k0 = blockIdx.y * 64, n0 = blockIdx.x * 64;
  const int t = threadIdx.x;
#pragma unroll
  for (int i = 0; i < 4; ++i) {
    const int kk = (t >> 4) + 16 * i;
    const int nn = (t & 15) * 4;
    const float4 v = *(const float4*)(src + (size_t)(k0 + kk) * H + n0 + nn);
    tile[nn + 0][kk] = v.x; tile[nn + 1][kk] = v.y;
    tile[nn + 2][kk] = v.z; tile[nn + 3][kk] = v.w;
  }
  __syncthreads();
  const int nn = t >> 2;
  const int kk = (t & 3) * 16;
  s16x8 o0, o1;
#pragma unroll
  for (int u = 0; u < 8; ++u) {
    o0[u] = f2bf(tile[nn][kk + u]);
    o1[u] = f2bf(tile[nn][kk + 8 + u]);
  }
  *(s16x8*)(dst + (size_t)(n0 + nn) * H + k0 + kk) = o0;
  *(s16x8*)(dst + (size_t)(n0 + nn) * H + k0 + kk + 8) = o1;
}

// ---------------- router: softmax -> top-2 -> per-expert gather lists ----------------
// cnt[6] must be zeroed before launch. idx[e][pos] = token (ushort),
// swgt[e][pos] = routing weight (bf16 bits).
__global__ void router_k(const float* __restrict__ x, const float* __restrict__ rw,
                         const float* __restrict__ rb, int* __restrict__ cnt,
                         unsigned short* __restrict__ idx, short* __restrict__ swgt) {
  const int lane = threadIdx.x & 63;
  const int b = blockIdx.x * 4 + (threadIdx.x >> 6);
  const float* xr = x + (size_t)b * H;
  float p[6] = {0.f, 0.f, 0.f, 0.f, 0.f, 0.f};
  for (int k = lane; k < H; k += 64) {
    const float xv = xr[k];
    const float* r = rw + k * 6;
#pragma unroll
    for (int e = 0; e < 6; ++e) p[e] += xv * r[e];
  }
#pragma unroll
  for (int e = 0; e < 6; ++e) {
    float v = p[e];
    for (int off = 32; off > 0; off >>= 1) v += __shfl_down(v, off);
    p[e] = v;
  }
  if (lane == 0) {
    float lg[6];
    float mx = -1e30f;
#pragma unroll
    for (int e = 0; e < 6; ++e) { lg[e] = p[e] + rb[e]; mx = fmaxf(mx, lg[e]); }
    float s = 0.f;
#pragma unroll
    for (int e = 0; e < 6; ++e) { lg[e] = __expf(lg[e] - mx); s += lg[e]; }
    const float inv = 1.f / s;
#pragma unroll
    for (int e = 0; e < 6; ++e) lg[e] *= inv;
    int i1 = 0;
#pragma unroll
    for (int e = 1; e < 6; ++e) if (lg[e] > lg[i1]) i1 = e;
    int i2 = (i1 == 0) ? 1 : 0;
#pragma unroll
    for (int e = 0; e < 6; ++e) if (e != i1 && lg[e] > lg[i2]) i2 = e;
    int p1 = atomicAdd(&cnt[i1], 1);
    idx[i1 * B_TOK + p1] = (unsigned short)b;
    swgt[i1 * B_TOK + p1] = f2bf(lg[i1]);
    int p2 = atomicAdd(&cnt[i2], 1);
    idx[i2 * B_TOK + p2] = (unsigned short)b;
    swgt[i2 * B_TOK + p2] = f2bf(lg[i2]);
  }
}

// ---------------- GEMM core: C[128x128] = A x Bt^T, bf16 MFMA ----------------
// LDS chunks in exact MFMA fragment order; optional row-gather on A through gidx.
__device__ __forceinline__ void gemm_core(const short* __restrict__ A,
                                          const short* __restrict__ Bt,
                                          short* As, short* Bs,
                                          int m0, int n0,
                                          const unsigned short* __restrict__ gidx,
                                          f32x4 acc[4][4]) {
  const int tid  = threadIdx.x;
  const int lane = tid & 63;
  const int w    = tid >> 6;
  const int q8   = (lane >> 4) * 8;
  const int r16  = lane & 15;
  const int wr   = w >> 1, wc = w & 1;

  // precompute per-chunk global base pointers (waves 0-1: A chunks, 2-3: B chunks)
  const short* gp[4];
  short* lp[4];
#pragma unroll
  for (int i = 0; i < 4; ++i) {
    const int c = w * 4 + i;
    if (c < 8) {
      int gr = m0 + c * 16 + r16;
      if (gidx) gr = gidx[gr];
      gp[i] = A + (size_t)gr * H + q8;
      lp[i] = As + c * 512;
    } else {
      const int nt = c - 8;
      gp[i] = Bt + (size_t)(n0 + nt * 16 + r16) * H + q8;
      lp[i] = Bs + nt * 512;
    }
  }

  for (int k0 = 0; k0 < H; k0 += 32) {
    __syncthreads();
#pragma unroll
    for (int i = 0; i < 4; ++i) load_lds16(gp[i] + k0, lp[i]);
    __syncthreads();
    s16x8 af[4], bfv[4];
#pragma unroll
    for (int i = 0; i < 4; ++i) af[i]  = *(const s16x8*)(As + (wr * 4 + i) * 512 + lane * 8);
#pragma unroll
    for (int j = 0; j < 4; ++j) bfv[j] = *(const s16x8*)(Bs + (wc * 4 + j) * 512 + lane * 8);
#pragma unroll
    for (int i = 0; i < 4; ++i)
#pragma unroll
      for (int j = 0; j < 4; ++j)
        acc[i][j] = __builtin_amdgcn_mfma_f32_16x16x32_bf16(af[i], bfv[j], acc[i][j], 0, 0, 0);
  }
}

// GEMM1: hm = tanh(A @ W1 + b1), bf16; GATHER=1 gathers A rows via idx, bounds via *cntp
template <int GATHER>
__global__ __launch_bounds__(256) void gemm1_k(const short* __restrict__ A,
                                               const short* __restrict__ Bt,
                                               const float* __restrict__ bias,
                                               short* __restrict__ Out,
                                               const unsigned short* __restrict__ idx,
                                               const int* __restrict__ cntp) {
  const unsigned short* gidx = nullptr;
  if (GATHER) {
    const int cnt = *cntp;
    if ((int)blockIdx.y * 128 >= cnt) return;
    gidx = idx;
  }
  __shared__ __align__(16) short As[4096];
  __shared__ __align__(16) short Bs[4096];
  const int n0 = blockIdx.x * 128, m0 = blockIdx.y * 128;
  f32x4 acc[4][4];
#pragma unroll
  for (int i = 0; i < 4; ++i)
#pragma unroll
    for (int j = 0; j < 4; ++j) acc[i][j] = (f32x4){0.f, 0.f, 0.f, 0.f};
  gemm_core(A, Bt, As, Bs, m0, n0, gidx, acc);
  const int lane = threadIdx.x & 63, w = threadIdx.x >> 6;
  const int wr = w >> 1, wc = w & 1, q = lane >> 4, c16 = lane & 15;
  const int mb = m0 + wr * 64, nb = n0 + wc * 64;
#pragma unroll
  for (int j = 0; j < 4; ++j) {
    const int col = nb + j * 16 + c16;
    const float bv = bias[col];
#pragma unroll
    for (int i = 0; i < 4; ++i)
#pragma unroll
      for (int r = 0; r < 4; ++r) {
        const int row = mb + i * 16 + q * 4 + r;
        Out[(size_t)row * H + col] = f2bf(tanhf(acc[i][j][r] + bv));
      }
  }
}

// GEMM2 epilogue modes: 0 = store, 1 = accumulate, 2 = weighted scatter-accumulate
template <int MODE>
__global__ __launch_bounds__(256) void gemm2_k(const short* __restrict__ A,
                                               const short* __restrict__ Bt,
                                               const float* __restrict__ bias,
                                               float* __restrict__ Out,
                                               const unsigned short* __restrict__ idx,
                                               const short* __restrict__ swgt,
                                               const int* __restrict__ cntp) {
  int cnt = B_TOK;
  if (MODE == 2) {
    cnt = *cntp;
    if ((int)blockIdx.y * 128 >= cnt) return;
  }
  __shared__ __align__(16) short As[4096];
  __shared__ __align__(16) short Bs[4096];
  const int n0 = blockIdx.x * 128, m0 = blockIdx.y * 128;
  f32x4 acc[4][4];
#pragma unroll
  for (int i = 0; i < 4; ++i)
#pragma unroll
    for (int j = 0; j < 4; ++j) acc[i][j] = (f32x4){0.f, 0.f, 0.f, 0.f};
  gemm_core(A, Bt, As, Bs, m0, n0, nullptr, acc);
  const int lane = threadIdx.x & 63, w = threadIdx.x >> 6;
  const int wr = w >> 1, wc = w & 1, q = lane >> 4, c16 = lane & 15;
  const int mb = m0 + wr * 64, nb = n0 + wc * 64;
#pragma unroll
  for (int i = 0; i < 4; ++i) {
    const int rbase = mb + i * 16 + q * 4;
    float sc[4];
    int tok[4];
#pragma unroll
    for (int r = 0; r < 4; ++r) {
      const int row = rbase + r;
      if (MODE == 2) {
        const bool ok = row < cnt;
        tok[r] = ok ? (int)idx[row] : -1;
        sc[r] = ok ? bf2f(swgt[row]) : 0.f;
      } else {
        tok[r] = row;
        sc[r] = 1.f;
      }
    }
#pragma unroll
    for (int j = 0; j < 4; ++j) {
      const int col = nb + j * 16 + c16;
      const float bv = bias[col];
#pragma unroll
      for (int r = 0; r < 4; ++r) {
        if (MODE == 2 && tok[r] < 0) continue;
        const size_t o = (size_t)tok[r] * H + col;
        const float v = acc[i][j][r] + bv;
        if (MODE == 0)      Out[o] = v;
        else if (MODE == 1) Out[o] += v;
        else                Out[o] += v * sc[r];
      }
    }
  }
}

extern "C" void kernel_launch(void* const* d_in, const int* in_sizes, int n_in,
                              void* d_out, int out_size, void* d_ws, size_t ws_size,
                              hipStream_t stream) {
  const float* x        = (const float*)d_in[0];
  const float* sw1      = (const float*)d_in[1];
  const float* sb1      = (const float*)d_in[2];
  const float* sw2      = (const float*)d_in[3];
  const float* sb2      = (const float*)d_in[4];
  const float* rw1      = (const float*)d_in[5];
  const float* rb1      = (const float*)d_in[6];
  const float* rw2      = (const float*)d_in[7];
  const float* rb2      = (const float*)d_in[8];
  const float* router_w = (const float*)d_in[9];
  const float* router_b = (const float*)d_in[10];
  float* out = (float*)d_out;

  // ws layout (high-water 96.38 MiB, under proven >=96.5 MiB):
  char* ws = (char*)d_ws;
  short*          xb   = (short*)(ws);                        // 32 MiB
  short*          w1t  = (short*)(ws + (size_t)33554432);     // 16 MiB
  short*          w2t  = (short*)(ws + (size_t)50331648);     // 16 MiB
  short*          hm   = (short*)(ws + (size_t)67108864);     // 32 MiB (reused)
  int*            cnt  = (int*)(ws + (size_t)100663296);      // 256 B
  unsigned short* idx  = (unsigned short*)(ws + (size_t)100663552);  // 192 KiB
  short*          swgt = (short*)(ws + (size_t)100860160);    // 192 KiB

  // zero cnt + idx (poisoned 0xAA each call; zeroed idx makes pad rows read token 0)
  hipMemsetAsync(cnt, 0, 256 + 6 * B_TOK * sizeof(unsigned short), stream);

  cvt_x_k<<<8192, 256, 0, stream>>>(x, xb);
  transpose_k<<<dim3(16, 16, 16), 256, 0, stream>>>(sw1, rw1, sw2, rw2, w1t, w2t);
  router_k<<<4096, 256, 0, stream>>>(x, router_w, router_b, cnt, idx, swgt);

  const dim3 g(8, 128);
  // shared expert 0: write; shared expert 1: accumulate
  gemm1_k<0><<<g, 256, 0, stream>>>(xb, w1t, sb1, hm, nullptr, nullptr);
  gemm2_k<0><<<g, 256, 0, stream>>>(hm, w2t, sb2, out, nullptr, nullptr, nullptr);
  gemm1_k<0><<<g, 256, 0, stream>>>(xb, w1t + (size_t)H * H, sb1 + H, hm, nullptr, nullptr);
  gemm2_k<1><<<g, 256, 0, stream>>>(hm, w2t + (size_t)H * H, sb2 + H, out, nullptr, nullptr, nullptr);

  // routed experts: gathered GEMM1 -> weighted scatter GEMM2 (serial, hm reused)
  for (int e = 0; e < 6; ++e) {
    gemm1_k<1><<<g, 256, 0, stream>>>(xb, w1t + (size_t)(2 + e) * H * H, rb1 + (size_t)e * H,
                                      hm, idx + (size_t)e * B_TOK, cnt + e);
    gemm2_k<2><<<g, 256, 0, stream>>>(hm, w2t + (size_t)(2 + e) * H * H, rb2 + (size_t)e * H,
                                      out, idx + (size_t)e * B_TOK, swgt + (size_t)e * B_TOK,
                                      cnt + e);
  }
}

// Round 3
// 1315.961 us; speedup vs baseline: 1.3860x; 1.1430x over previous
//
#include <hip/hip_runtime.h>
#include <hip/hip_bf16.h>

#define H 1024
#define B_TOK 16384

typedef __attribute__((ext_vector_type(8))) short s16x8;
typedef __attribute__((ext_vector_type(4))) float f32x4;

__device__ __forceinline__ short f2bf(float f) {
  __hip_bfloat16 h = __float2bfloat16(f);
  return __builtin_bit_cast(short, h);
}
__device__ __forceinline__ float bf2f(short s) {
  __hip_bfloat16 h = __builtin_bit_cast(__hip_bfloat16, s);
  return __bfloat162float(h);
}

__device__ __forceinline__ void load_lds16(const short* g, short* l) {
  __builtin_amdgcn_global_load_lds((const __attribute__((address_space(1))) void*)g,
                                   (__attribute__((address_space(3))) void*)l,
                                   16, 0, 0);
}

// ---------------- convert x -> bf16 ----------------
__global__ void cvt_x_k(const float* __restrict__ x, short* __restrict__ xb) {
  const size_t i = ((size_t)blockIdx.x * blockDim.x + threadIdx.x) * 8;
  const float4 a = *(const float4*)(x + i);
  const float4 b = *(const float4*)(x + i + 4);
  s16x8 v;
  v[0] = f2bf(a.x); v[1] = f2bf(a.y); v[2] = f2bf(a.z); v[3] = f2bf(a.w);
  v[4] = f2bf(b.x); v[5] = f2bf(b.y); v[6] = f2bf(b.z); v[7] = f2bf(b.w);
  *(s16x8*)(xb + i) = v;
}

// ---------------- transpose+convert weights ----------------
// z 0..7 : w1 (shared e0,e1 then routed e0..5) -> w1t[z] [1024][1024], ld 1024
// z 8..9 : shared w2 -> w2t_sh [1024][2048], column offset e*1024 (K-merged)
// z 10..15: routed w2 -> w2t_r[e] [1024][1024], ld 1024
__global__ void transpose_k(const float* __restrict__ sw1, const float* __restrict__ rw1,
                            const float* __restrict__ sw2, const float* __restrict__ rw2,
                            short* __restrict__ w1t, short* __restrict__ w2t_sh,
                            short* __restrict__ w2t_r) {
  __shared__ float tile[64][65];
  const int z = blockIdx.z;
  const float* src;
  short* dst;
  int ldd = H, koff = 0;
  if (z < 8) {
    src = (z < 2) ? sw1 + (size_t)z * H * H : rw1 + (size_t)(z - 2) * H * H;
    dst = w1t + (size_t)z * H * H;
  } else if (z < 10) {
    const int e = z - 8;
    src = sw2 + (size_t)e * H * H;
    dst = w2t_sh; ldd = 2048; koff = e * 1024;
  } else {
    const int e = z - 10;
    src = rw2 + (size_t)e * H * H;
    dst = w2t_r + (size_t)e * H * H;
  }
  const int k0 = blockIdx.y * 64, n0 = blockIdx.x * 64;
  const int t = threadIdx.x;
#pragma unroll
  for (int i = 0; i < 4; ++i) {
    const int kk = (t >> 4) + 16 * i;
    const int nn = (t & 15) * 4;
    const float4 v = *(const float4*)(src + (size_t)(k0 + kk) * H + n0 + nn);
    tile[nn + 0][kk] = v.x; tile[nn + 1][kk] = v.y;
    tile[nn + 2][kk] = v.z; tile[nn + 3][kk] = v.w;
  }
  __syncthreads();
  const int nn = t >> 2;
  const int kk = (t & 3) * 16;
  s16x8 o0, o1;
#pragma unroll
  for (int u = 0; u < 8; ++u) {
    o0[u] = f2bf(tile[nn][kk + u]);
    o1[u] = f2bf(tile[nn][kk + 8 + u]);
  }
  short* drow = dst + (size_t)(n0 + nn) * ldd + koff + k0 + kk;
  *(s16x8*)(drow) = o0;
  *(s16x8*)(drow + 8) = o1;
}

// ---------------- router phase 1: logits -> softmax -> top-2, NO atomics ----------------
// tk[b] = int2{ e1 | (w1_bf16_bits<<16), e2 | (w2_bf16_bits<<16) }
__global__ void logits_k(const float* __restrict__ x, const float* __restrict__ rw,
                         const float* __restrict__ rb, int2* __restrict__ tk) {
  const int lane = threadIdx.x & 63;
  const int b = blockIdx.x * 4 + (threadIdx.x >> 6);
  const float* xr = x + (size_t)b * H;
  float p[6] = {0.f, 0.f, 0.f, 0.f, 0.f, 0.f};
  for (int k = lane; k < H; k += 64) {
    const float xv = xr[k];
    const float* r = rw + k * 6;
#pragma unroll
    for (int e = 0; e < 6; ++e) p[e] += xv * r[e];
  }
#pragma unroll
  for (int e = 0; e < 6; ++e) {
    float v = p[e];
    for (int off = 32; off > 0; off >>= 1) v += __shfl_down(v, off);
    p[e] = v;
  }
  if (lane == 0) {
    float lg[6];
    float mx = -1e30f;
#pragma unroll
    for (int e = 0; e < 6; ++e) { lg[e] = p[e] + rb[e]; mx = fmaxf(mx, lg[e]); }
    float s = 0.f;
#pragma unroll
    for (int e = 0; e < 6; ++e) { lg[e] = __expf(lg[e] - mx); s += lg[e]; }
    const float inv = 1.f / s;
#pragma unroll
    for (int e = 0; e < 6; ++e) lg[e] *= inv;
    int i1 = 0;
#pragma unroll
    for (int e = 1; e < 6; ++e) if (lg[e] > lg[i1]) i1 = e;
    int i2 = (i1 == 0) ? 1 : 0;
#pragma unroll
    for (int e = 0; e < 6; ++e) if (e != i1 && lg[e] > lg[i2]) i2 = e;
    int2 v;
    v.x = i1 | ((int)(unsigned short)f2bf(lg[i1]) << 16);
    v.y = i2 | ((int)(unsigned short)f2bf(lg[i2]) << 16);
    tk[b] = v;
  }
}

// ---------------- router phase 2: block-aggregated scatter (6 atomics/block) ----------------
__global__ void scatter_k(const int2* __restrict__ tk, int* __restrict__ cnt,
                          unsigned short* __restrict__ idx, short* __restrict__ swgt) {
  __shared__ int lcnt[6];
  __shared__ int lbase[6];
  const int t = threadIdx.x;
  if (t < 6) lcnt[t] = 0;
  __syncthreads();
  const int tok = blockIdx.x * 256 + t;
  const int2 v = tk[tok];
  const int e1 = v.x & 0xffff, e2 = v.y & 0xffff;
  const short w1b = (short)((unsigned)v.x >> 16);
  const short w2b = (short)((unsigned)v.y >> 16);
  const int p1 = atomicAdd(&lcnt[e1], 1);
  const int p2 = atomicAdd(&lcnt[e2], 1);
  __syncthreads();
  if (t < 6) lbase[t] = atomicAdd(&cnt[t], lcnt[t]);
  __syncthreads();
  const int o1 = e1 * B_TOK + lbase[e1] + p1;
  idx[o1] = (unsigned short)tok; swgt[o1] = w1b;
  const int o2 = e2 * B_TOK + lbase[e2] + p2;
  idx[o2] = (unsigned short)tok; swgt[o2] = w2b;
}

// ---------------- GEMM core: C[128x128] = A x Bt^T, bf16 MFMA ----------------
// m-tiles on blockIdx.x (divisible by 8) => all n-blocks of an m-tile share an XCD.
__device__ __forceinline__ void gemm_core(const short* __restrict__ A, int lda,
                                          const short* __restrict__ Bt, int ldb, int K,
                                          short* As, short* Bs,
                                          int m0, int n0,
                                          const unsigned short* __restrict__ gidx,
                                          f32x4 acc[4][4]) {
  const int tid  = threadIdx.x;
  const int lane = tid & 63;
  const int w    = tid >> 6;
  const int q8   = (lane >> 4) * 8;
  const int r16  = lane & 15;
  const int wr   = w >> 1, wc = w & 1;

  const short* gp[4];
  short* lp[4];
#pragma unroll
  for (int i = 0; i < 4; ++i) {
    const int c = w * 4 + i;
    if (c < 8) {
      int gr = m0 + c * 16 + r16;
      if (gidx) gr = gidx[gr];
      gp[i] = A + (size_t)gr * lda + q8;
      lp[i] = As + c * 512;
    } else {
      const int nt = c - 8;
      gp[i] = Bt + (size_t)(n0 + nt * 16 + r16) * ldb + q8;
      lp[i] = Bs + nt * 512;
    }
  }

  for (int k0 = 0; k0 < K; k0 += 32) {
    __syncthreads();
#pragma unroll
    for (int i = 0; i < 4; ++i) load_lds16(gp[i] + k0, lp[i]);
    __syncthreads();
    s16x8 af[4], bfv[4];
#pragma unroll
    for (int i = 0; i < 4; ++i) af[i]  = *(const s16x8*)(As + (wr * 4 + i) * 512 + lane * 8);
#pragma unroll
    for (int j = 0; j < 4; ++j) bfv[j] = *(const s16x8*)(Bs + (wc * 4 + j) * 512 + lane * 8);
#pragma unroll
    for (int i = 0; i < 4; ++i)
#pragma unroll
      for (int j = 0; j < 4; ++j)
        acc[i][j] = __builtin_amdgcn_mfma_f32_16x16x32_bf16(af[i], bfv[j], acc[i][j], 0, 0, 0);
  }
}

// GEMM1: Out = tanh(A @ W1 + b1) bf16; GATHER=1 gathers A rows via idx, bound via *cntp
template <int GATHER>
__global__ __launch_bounds__(256) void gemm1_k(const short* __restrict__ A, int lda,
                                               const short* __restrict__ Bt, int ldb, int K,
                                               const float* __restrict__ bias,
                                               short* __restrict__ Out, int ldo,
                                               const unsigned short* __restrict__ idx,
                                               const int* __restrict__ cntp) {
  const unsigned short* gidx = nullptr;
  if (GATHER) {
    const int cnt = *cntp;
    if ((int)blockIdx.x * 128 >= cnt) return;
    gidx = idx;
  }
  __shared__ __align__(16) short As[4096];
  __shared__ __align__(16) short Bs[4096];
  const int m0 = blockIdx.x * 128, n0 = blockIdx.y * 128;
  f32x4 acc[4][4];
#pragma unroll
  for (int i = 0; i < 4; ++i)
#pragma unroll
    for (int j = 0; j < 4; ++j) acc[i][j] = (f32x4){0.f, 0.f, 0.f, 0.f};
  gemm_core(A, lda, Bt, ldb, K, As, Bs, m0, n0, gidx, acc);
  const int lane = threadIdx.x & 63, w = threadIdx.x >> 6;
  const int wr = w >> 1, wc = w & 1, q = lane >> 4, c16 = lane & 15;
  const int mb = m0 + wr * 64, nb = n0 + wc * 64;
#pragma unroll
  for (int j = 0; j < 4; ++j) {
    const int col = nb + j * 16 + c16;
    const float bv = bias[col];
#pragma unroll
    for (int i = 0; i < 4; ++i)
#pragma unroll
      for (int r = 0; r < 4; ++r) {
        const int row = mb + i * 16 + q * 4 + r;
        Out[(size_t)row * ldo + col] = f2bf(tanhf(acc[i][j][r] + bv));
      }
  }
}

// GEMM2 modes: 0 = store, 1 = accumulate, 2 = weighted scatter-accumulate
template <int MODE>
__global__ __launch_bounds__(256) void gemm2_k(const short* __restrict__ A, int lda,
                                               const short* __restrict__ Bt, int ldb, int K,
                                               const float* __restrict__ bias_a,
                                               const float* __restrict__ bias_b,
                                               float* __restrict__ Out,
                                               const unsigned short* __restrict__ idx,
                                               const short* __restrict__ swgt,
                                               const int* __restrict__ cntp) {
  int cnt = B_TOK;
  if (MODE == 2) {
    cnt = *cntp;
    if ((int)blockIdx.x * 128 >= cnt) return;
  }
  __shared__ __align__(16) short As[4096];
  __shared__ __align__(16) short Bs[4096];
  const int m0 = blockIdx.x * 128, n0 = blockIdx.y * 128;
  f32x4 acc[4][4];
#pragma unroll
  for (int i = 0; i < 4; ++i)
#pragma unroll
    for (int j = 0; j < 4; ++j) acc[i][j] = (f32x4){0.f, 0.f, 0.f, 0.f};
  gemm_core(A, lda, Bt, ldb, K, As, Bs, m0, n0, nullptr, acc);
  const int lane = threadIdx.x & 63, w = threadIdx.x >> 6;
  const int wr = w >> 1, wc = w & 1, q = lane >> 4, c16 = lane & 15;
  const int mb = m0 + wr * 64, nb = n0 + wc * 64;
#pragma unroll
  for (int i = 0; i < 4; ++i) {
    const int rbase = mb + i * 16 + q * 4;
    float sc[4];
    int tok[4];
#pragma unroll
    for (int r = 0; r < 4; ++r) {
      const int row = rbase + r;
      if (MODE == 2) {
        const bool ok = row < cnt;
        tok[r] = ok ? (int)idx[row] : -1;
        sc[r] = ok ? bf2f(swgt[row]) : 0.f;
      } else {
        tok[r] = row;
        sc[r] = 1.f;
      }
    }
#pragma unroll
    for (int j = 0; j < 4; ++j) {
      const int col = nb + j * 16 + c16;
      const float bv = bias_a[col] + (bias_b ? bias_b[col] : 0.f);
#pragma unroll
      for (int r = 0; r < 4; ++r) {
        if (MODE == 2 && tok[r] < 0) continue;
        const size_t o = (size_t)tok[r] * H + col;
        const float v = acc[i][j][r] + bv;
        if (MODE == 0)      Out[o] = v;
        else if (MODE == 1) Out[o] += v;
        else                Out[o] += v * sc[r];
      }
    }
  }
}

extern "C" void kernel_launch(void* const* d_in, const int* in_sizes, int n_in,
                              void* d_out, int out_size, void* d_ws, size_t ws_size,
                              hipStream_t stream) {
  const float* x        = (const float*)d_in[0];
  const float* sw1      = (const float*)d_in[1];
  const float* sb1      = (const float*)d_in[2];  // [2][1024] flat == 2048-concat
  const float* sw2      = (const float*)d_in[3];
  const float* sb2      = (const float*)d_in[4];
  const float* rw1      = (const float*)d_in[5];
  const float* rb1      = (const float*)d_in[6];
  const float* rw2      = (const float*)d_in[7];
  const float* rb2      = (const float*)d_in[8];
  const float* router_w = (const float*)d_in[9];
  const float* router_b = (const float*)d_in[10];
  float* out = (float*)d_out;

  char* ws = (char*)d_ws;
  short* xb     = (short*)(ws);                     // 32 MiB
  short* w1t    = (short*)(ws + (size_t)33554432);  // 16 MiB (8 x [1024][1024])
  short* w2t_sh = (short*)(ws + (size_t)50331648);  // 4 MiB  ([1024][2048] K-merged)
  short* w2t_r  = (short*)(ws + (size_t)54525952);  // 12 MiB (6 x [1024][1024])
  short* hm     = (short*)(ws + (size_t)67108864);  // 32 or 64 MiB
  int2*  tk     = (int2*)(ws + (size_t)67108864);   // 128 KiB, consumed before hm is written

  // merged shared path needs hm = [16384][2048] bf16 = 64 MiB
  const size_t tail_merged = (size_t)67108864 + 67108864;
  const size_t need_merged = tail_merged + 256 + 2 * 6 * B_TOK * sizeof(short);
  const bool merged = ws_size >= need_merged;
  const size_t tail = (size_t)67108864 + (merged ? 67108864 : 33554432);
  int*            cnt  = (int*)(ws + tail);
  unsigned short* idx  = (unsigned short*)(ws + tail + 256);
  short*          swgt = (short*)(ws + tail + 256 + 6 * B_TOK * sizeof(unsigned short));

  hipMemsetAsync(cnt, 0, 256 + 6 * B_TOK * sizeof(unsigned short), stream);

  cvt_x_k<<<8192, 256, 0, stream>>>(x, xb);
  transpose_k<<<dim3(16, 16, 16), 256, 0, stream>>>(sw1, rw1, sw2, rw2, w1t, w2t_sh, w2t_r);
  logits_k<<<4096, 256, 0, stream>>>(x, router_w, router_b, tk);
  scatter_k<<<64, 256, 0, stream>>>(tk, cnt, idx, swgt);

  if (merged) {
    // shared experts fused: GEMM1 N=2048, GEMM2 K=2048, single out write
    gemm1_k<0><<<dim3(128, 16), 256, 0, stream>>>(xb, H, w1t, H, H, sb1, hm, 2048,
                                                  nullptr, nullptr);
    gemm2_k<0><<<dim3(128, 8), 256, 0, stream>>>(hm, 2048, w2t_sh, 2048, 2048,
                                                 sb2, sb2 + H, out, nullptr, nullptr, nullptr);
  } else {
    gemm1_k<0><<<dim3(128, 8), 256, 0, stream>>>(xb, H, w1t, H, H, sb1, hm, H,
                                                 nullptr, nullptr);
    gemm2_k<0><<<dim3(128, 8), 256, 0, stream>>>(hm, H, w2t_sh, 2048, H,
                                                 sb2, nullptr, out, nullptr, nullptr, nullptr);
    gemm1_k<0><<<dim3(128, 8), 256, 0, stream>>>(xb, H, w1t + (size_t)H * H, H, H, sb1 + H,
                                                 hm, H, nullptr, nullptr);
    gemm2_k<1><<<dim3(128, 8), 256, 0, stream>>>(hm, H, w2t_sh + 1024, 2048, H,
                                                 sb2 + H, nullptr, out, nullptr, nullptr, nullptr);
  }

  // routed experts: gathered GEMM1 -> weighted scatter GEMM2
  for (int e = 0; e < 6; ++e) {
    gemm1_k<1><<<dim3(128, 8), 256, 0, stream>>>(xb, H, w1t + (size_t)(2 + e) * H * H, H, H,
                                                 rb1 + (size_t)e * H, hm, H,
                                                 idx + (size_t)e * B_TOK, cnt + e);
    gemm2_k<2><<<dim3(128, 8), 256, 0, stream>>>(hm, H, w2t_r + (size_t)e * H * H, H, H,
                                                 rb2 + (size_t)e * H, nullptr, out,
                                                 idx + (size_t)e * B_TOK,
                                                 swgt + (size_t)e * B_TOK, cnt + e);
  }
}

// Round 5
// 831.037 us; speedup vs baseline: 2.1947x; 1.5835x over previous
//
#include <hip/hip_runtime.h>
#include <hip/hip_bf16.h>

#define H 1024
#define B_TOK 16384
#define RTILES 262            // covers worst padded slot total 33408 (261 tiles) + margin
#define RCAP   (RTILES * 128) // asg / routed-hm row capacity (33536)

typedef __attribute__((ext_vector_type(8))) short s16x8;
typedef __attribute__((ext_vector_type(4))) float f32x4;

__device__ __forceinline__ short f2bf(float f) {
  __hip_bfloat16 h = __float2bfloat16(f);
  return __builtin_bit_cast(short, h);
}
__device__ __forceinline__ float bf2f(short s) {
  __hip_bfloat16 h = __builtin_bit_cast(__hip_bfloat16, s);
  return __bfloat162float(h);
}

__device__ __forceinline__ void load_lds16(const short* g, short* l) {
  __builtin_amdgcn_global_load_lds((const __attribute__((address_space(1))) void*)g,
                                   (__attribute__((address_space(3))) void*)l,
                                   16, 0, 0);
}

// ---------------- convert x -> bf16 ----------------
__global__ void cvt_x_k(const float* __restrict__ x, short* __restrict__ xb) {
  const size_t i = ((size_t)blockIdx.x * blockDim.x + threadIdx.x) * 8;
  const float4 a = *(const float4*)(x + i);
  const float4 b = *(const float4*)(x + i + 4);
  s16x8 v;
  v[0] = f2bf(a.x); v[1] = f2bf(a.y); v[2] = f2bf(a.z); v[3] = f2bf(a.w);
  v[4] = f2bf(b.x); v[5] = f2bf(b.y); v[6] = f2bf(b.z); v[7] = f2bf(b.w);
  *(s16x8*)(xb + i) = v;
}

// ---------------- transpose+convert weights ----------------
// z 0..7: w1 (shared e0,e1 then routed) -> w1t [8][1024][1024]
// z 8..9: shared w2 -> w2t_sh [1024][2048] (K-merged, col offset e*1024)
// z 10..15: routed w2 -> w2t_r [6][1024][1024]
__global__ void transpose_k(const float* __restrict__ sw1, const float* __restrict__ rw1,
                            const float* __restrict__ sw2, const float* __restrict__ rw2,
                            short* __restrict__ w1t, short* __restrict__ w2t_sh,
                            short* __restrict__ w2t_r) {
  __shared__ float tile[64][65];
  const int z = blockIdx.z;
  const float* src;
  short* dst;
  int ldd = H, koff = 0;
  if (z < 8) {
    src = (z < 2) ? sw1 + (size_t)z * H * H : rw1 + (size_t)(z - 2) * H * H;
    dst = w1t + (size_t)z * H * H;
  } else if (z < 10) {
    const int e = z - 8;
    src = sw2 + (size_t)e * H * H;
    dst = w2t_sh; ldd = 2048; koff = e * 1024;
  } else {
    const int e = z - 10;
    src = rw2 + (size_t)e * H * H;
    dst = w2t_r + (size_t)e * H * H;
  }
  const int k0 = blockIdx.y * 64, n0 = blockIdx.x * 64;
  const int t = threadIdx.x;
#pragma unroll
  for (int i = 0; i < 4; ++i) {
    const int kk = (t >> 4) + 16 * i;
    const int nn = (t & 15) * 4;
    const float4 v = *(const float4*)(src + (size_t)(k0 + kk) * H + n0 + nn);
    tile[nn + 0][kk] = v.x; tile[nn + 1][kk] = v.y;
    tile[nn + 2][kk] = v.z; tile[nn + 3][kk] = v.w;
  }
  __syncthreads();
  const int nn = t >> 2;
  const int kk = (t & 3) * 16;
  s16x8 o0, o1;
#pragma unroll
  for (int u = 0; u < 8; ++u) {
    o0[u] = f2bf(tile[nn][kk + u]);
    o1[u] = f2bf(tile[nn][kk + 8 + u]);
  }
  short* drow = dst + (size_t)(n0 + nn) * ldd + koff + k0 + kk;
  *(s16x8*)(drow) = o0;
  *(s16x8*)(drow + 8) = o1;
}

// ---------------- router phase 1: logits -> softmax -> top-2 ----------------
__global__ void logits_k(const float* __restrict__ x, const float* __restrict__ rw,
                         const float* __restrict__ rb, int2* __restrict__ tk) {
  const int lane = threadIdx.x & 63;
  const int b = blockIdx.x * 4 + (threadIdx.x >> 6);
  const float* xr = x + (size_t)b * H;
  float p[6] = {0.f, 0.f, 0.f, 0.f, 0.f, 0.f};
  for (int k = lane; k < H; k += 64) {
    const float xv = xr[k];
    const float* r = rw + k * 6;
#pragma unroll
    for (int e = 0; e < 6; ++e) p[e] += xv * r[e];
  }
#pragma unroll
  for (int e = 0; e < 6; ++e) {
    float v = p[e];
    for (int off = 32; off > 0; off >>= 1) v += __shfl_down(v, off);
    p[e] = v;
  }
  if (lane == 0) {
    float lg[6];
    float mx = -1e30f;
#pragma unroll
    for (int e = 0; e < 6; ++e) { lg[e] = p[e] + rb[e]; mx = fmaxf(mx, lg[e]); }
    float s = 0.f;
#pragma unroll
    for (int e = 0; e < 6; ++e) { lg[e] = __expf(lg[e] - mx); s += lg[e]; }
    const float inv = 1.f / s;
#pragma unroll
    for (int e = 0; e < 6; ++e) lg[e] *= inv;
    int i1 = 0;
#pragma unroll
    for (int e = 1; e < 6; ++e) if (lg[e] > lg[i1]) i1 = e;
    int i2 = (i1 == 0) ? 1 : 0;
#pragma unroll
    for (int e = 0; e < 6; ++e) if (e != i1 && lg[e] > lg[i2]) i2 = e;
    int2 v;
    v.x = i1 | ((int)(unsigned short)f2bf(lg[i1]) << 16);
    v.y = i2 | ((int)(unsigned short)f2bf(lg[i2]) << 16);
    tk[b] = v;
  }
}

// g layout: g[0..5]=cnt, g[8..13]=region starts (128-padded), g[14]=padded total,
// g[16..21]=fill counters
__global__ void hist_k(const int2* __restrict__ tk, int* __restrict__ g) {
  __shared__ int h[6];
  const int t = threadIdx.x;
  if (t < 6) h[t] = 0;
  __syncthreads();
  const int2 v = tk[blockIdx.x * 256 + t];
  atomicAdd(&h[v.x & 0xffff], 1);
  atomicAdd(&h[v.y & 0xffff], 1);
  __syncthreads();
  if (t < 6) atomicAdd(&g[t], h[t]);
}

__global__ void prefix_k(int* __restrict__ g) {
  if (threadIdx.x == 0) {
    int run = 0;
#pragma unroll
    for (int e = 0; e < 6; ++e) {
      g[8 + e] = run; g[16 + e] = run;
      run += (g[e] + 127) & ~127;
    }
    g[14] = run;   // <= 33408 worst case (round-4 bug: slots past 32768 were dropped)
  }
}

// scatter into compacted slot space; asg pre-memset to 0xFF (sentinel -1)
__global__ void scatter_k(const int2* __restrict__ tk, int* __restrict__ g,
                          int* __restrict__ asg) {
  __shared__ int lcnt[6];
  __shared__ int lbase[6];
  const int t = threadIdx.x;
  if (t < 6) lcnt[t] = 0;
  __syncthreads();
  const int tok = blockIdx.x * 256 + t;
  const int2 v = tk[tok];
  const int e1 = v.x & 0xffff, e2 = v.y & 0xffff;
  const int p1 = atomicAdd(&lcnt[e1], 1);
  const int p2 = atomicAdd(&lcnt[e2], 1);
  __syncthreads();
  if (t < 6) lbase[t] = atomicAdd(&g[16 + t], lcnt[t]);
  __syncthreads();
  asg[lbase[e1] + p1] = tok | (v.x & 0xffff0000);
  asg[lbase[e2] + p2] = tok | (v.y & 0xffff0000);
}

// ---------------- GEMM core, BK=64: C[128x128] = A x Bt^T ----------------
// smem: 32 chunks x 512 shorts; chunk (2*c2+kh) holds row-tile c2, k-half kh in
// exact MFMA fragment order (lane l: row c2*16+(l&15), k=kh*32+(l>>4)*8+j).
__device__ __forceinline__ void gemm_core64(const short* __restrict__ A, int lda,
                                            const short* __restrict__ Bt, int ldb, int K,
                                            short* smem, int m0, int n0,
                                            const int* __restrict__ asg, int acap,
                                            f32x4 acc[4][4]) {
  const int tid = threadIdx.x, lane = tid & 63, w = tid >> 6;
  const int q8 = (lane >> 4) * 8, r16 = lane & 15;
  const int wr = w >> 1, wc = w & 1;

  const short* gp[4];
#pragma unroll
  for (int ii = 0; ii < 4; ++ii) {
    const int c2 = w * 4 + ii;      // row-tile index 0..15 (0..7 A, 8..15 B)
    if (c2 < 8) {
      int slot = m0 + c2 * 16 + r16;
      int gr;
      if (asg) {
        int tv = asg[slot] & 0xffff;
        gr = tv < B_TOK ? tv : B_TOK - 1;   // sentinel/pad -> clamp to any valid row
      } else {
        gr = slot < acap ? slot : acap - 1;
      }
      gp[ii] = A + (size_t)gr * lda + q8;
    } else {
      gp[ii] = Bt + (size_t)(n0 + (c2 - 8) * 16 + r16) * ldb + q8;
    }
  }
  short* lbase = smem + w * 4096;

  for (int k0 = 0; k0 < K; k0 += 64) {
    __syncthreads();
#pragma unroll
    for (int i = 0; i < 8; ++i)
      load_lds16(gp[i >> 1] + k0 + (i & 1) * 32, lbase + i * 512);
    __syncthreads();
#pragma unroll
    for (int s = 0; s < 2; ++s) {
      s16x8 af[4], bfv[4];
#pragma unroll
      for (int i = 0; i < 4; ++i)
        af[i] = *(const s16x8*)(smem + ((wr * 4 + i) * 2 + s) * 512 + lane * 8);
#pragma unroll
      for (int j = 0; j < 4; ++j)
        bfv[j] = *(const s16x8*)(smem + (16 + (wc * 4 + j) * 2 + s) * 512 + lane * 8);
#pragma unroll
      for (int i = 0; i < 4; ++i)
#pragma unroll
        for (int j = 0; j < 4; ++j)
          acc[i][j] = __builtin_amdgcn_mfma_f32_16x16x32_bf16(af[i], bfv[j], acc[i][j], 0, 0, 0);
    }
  }
}

// GEMM1: Out = tanh(A @ W1 + b1) bf16, LDS-staged coalesced store.
// ROUTED=1: batched routed experts (expert from region starts, A-gather via asg)
template <int ROUTED>
__global__ __launch_bounds__(256) void gemm1_k(const short* __restrict__ A, int lda,
                                               const short* __restrict__ W1, int ldb, int K,
                                               const float* __restrict__ b1,
                                               short* __restrict__ Out, int ldo,
                                               const int* __restrict__ asg,
                                               const int* __restrict__ g, int rowcap) {
  const int m0 = blockIdx.x * 128, n0 = blockIdx.y * 128;
  const short* Bt = W1;
  const float* bias = b1;
  if (ROUTED) {
    if (m0 >= g[14]) return;
    int e = 0;
#pragma unroll
    for (int j = 1; j < 6; ++j) if (m0 >= g[8 + j]) e = j;
    Bt = W1 + (size_t)e * H * H;
    bias = b1 + (size_t)e * H;
  }
  __shared__ __align__(16) short smem[16384];
  f32x4 acc[4][4];
#pragma unroll
  for (int i = 0; i < 4; ++i)
#pragma unroll
    for (int j = 0; j < 4; ++j) acc[i][j] = (f32x4){0.f, 0.f, 0.f, 0.f};
  gemm_core64(A, lda, Bt, ldb, K, smem, m0, n0, ROUTED ? asg : nullptr, 1 << 30, acc);

  const int tid = threadIdx.x, lane = tid & 63, w = tid >> 6;
  const int wr = w >> 1, wc = w & 1, q = lane >> 4, c16 = lane & 15;
  __syncthreads();
#pragma unroll
  for (int j = 0; j < 4; ++j) {
    const int colL = wc * 64 + j * 16 + c16;
    const float bv = bias[n0 + colL];
#pragma unroll
    for (int i = 0; i < 4; ++i)
#pragma unroll
      for (int r = 0; r < 4; ++r)
        smem[(wr * 64 + i * 16 + q * 4 + r) * 128 + colL] = f2bf(tanhf(acc[i][j][r] + bv));
  }
  __syncthreads();
#pragma unroll
  for (int p = 0; p < 8; ++p) {
    const int rowL = p * 16 + (tid >> 4);
    const int colL = (tid & 15) * 8;
    const int gr = m0 + rowL;
    if (gr < rowcap)
      *(s16x8*)(Out + (size_t)gr * ldo + n0 + colL) = *(const s16x8*)(smem + rowL * 128 + colL);
  }
}

// GEMM2: MODE 0 = merged shared store (LDS-staged fp32), MODE 3 = routed atomic-scatter
template <int MODE>
__global__ __launch_bounds__(256) void gemm2_k(const short* __restrict__ A, int lda,
                                               const short* __restrict__ W2, int ldb, int K,
                                               const float* __restrict__ b2a,
                                               const float* __restrict__ b2b,
                                               float* __restrict__ Out,
                                               const int* __restrict__ asg,
                                               const int* __restrict__ g, int acap) {
  const int m0 = blockIdx.x * 128, n0 = blockIdx.y * 128;
  const short* Bt = W2;
  const float* bias = b2a;
  if (MODE == 3) {
    if (m0 >= g[14]) return;
    int e = 0;
#pragma unroll
    for (int j = 1; j < 6; ++j) if (m0 >= g[8 + j]) e = j;
    Bt = W2 + (size_t)e * H * H;
    bias = b2a + (size_t)e * H;
  }
  __shared__ __align__(16) short smem[16384];
  f32x4 acc[4][4];
#pragma unroll
  for (int i = 0; i < 4; ++i)
#pragma unroll
    for (int j = 0; j < 4; ++j) acc[i][j] = (f32x4){0.f, 0.f, 0.f, 0.f};
  gemm_core64(A, lda, Bt, ldb, K, smem, m0, n0, nullptr, acap, acc);

  const int tid = threadIdx.x, lane = tid & 63, w = tid >> 6;
  const int wr = w >> 1, wc = w & 1, q = lane >> 4, c16 = lane & 15;

  if (MODE == 0) {
    float* cs = (float*)smem;  // [64][128]
    __syncthreads();
#pragma unroll
    for (int half = 0; half < 2; ++half) {
      if (wr == half) {
#pragma unroll
        for (int j = 0; j < 4; ++j) {
          const int colL = wc * 64 + j * 16 + c16;
          const float bv = b2a[n0 + colL] + b2b[n0 + colL];
#pragma unroll
          for (int i = 0; i < 4; ++i)
#pragma unroll
            for (int r = 0; r < 4; ++r)
              cs[(i * 16 + q * 4 + r) * 128 + colL] = acc[i][j][r] + bv;
        }
      }
      __syncthreads();
#pragma unroll
      for (int p = 0; p < 8; ++p) {
        const int rowL = p * 8 + (tid >> 5);
        const int colL = (tid & 31) * 4;
        *(float4*)(Out + (size_t)(m0 + half * 64 + rowL) * H + n0 + colL) =
            *(const float4*)(cs + rowL * 128 + colL);
      }
      __syncthreads();
    }
  } else {
    const int mb = m0 + wr * 64, nb = n0 + wc * 64;
#pragma unroll
    for (int i = 0; i < 4; ++i) {
      int av[4];
#pragma unroll
      for (int r = 0; r < 4; ++r) av[r] = asg[mb + i * 16 + q * 4 + r];
#pragma unroll
      for (int j = 0; j < 4; ++j) {
        const int col = nb + j * 16 + c16;
        const float bv = bias[col];
#pragma unroll
        for (int r = 0; r < 4; ++r) {
          if (av[r] == -1) continue;   // pad slot
          const int tok = av[r] & 0xffff;
          const float wt = bf2f((short)((unsigned)av[r] >> 16));
          atomicAdd(&Out[(size_t)tok * H + col], (acc[i][j][r] + bv) * wt);
        }
      }
    }
  }
}

extern "C" void kernel_launch(void* const* d_in, const int* in_sizes, int n_in,
                              void* d_out, int out_size, void* d_ws, size_t ws_size,
                              hipStream_t stream) {
  const float* x        = (const float*)d_in[0];
  const float* sw1      = (const float*)d_in[1];
  const float* sb1      = (const float*)d_in[2];  // [2][1024] flat
  const float* sw2      = (const float*)d_in[3];
  const float* sb2      = (const float*)d_in[4];
  const float* rw1      = (const float*)d_in[5];
  const float* rb1      = (const float*)d_in[6];
  const float* rw2      = (const float*)d_in[7];
  const float* rb2      = (const float*)d_in[8];
  const float* router_w = (const float*)d_in[9];
  const float* router_b = (const float*)d_in[10];
  float* out = (float*)d_out;

  // ws layout (high-water 128.13 MiB, within proven >=128.38 MiB):
  //   xb      [0,          32 MiB)
  //   w1t     [32 MiB,     48 MiB)   [8][1024][1024]
  //   w2t_r   [48 MiB,     60 MiB)   [6][1024][1024]
  //   w2t_sh  [60 MiB,     64 MiB)   [1024][2048]   (dead after shared gemm2)
  //   hm_sh   [64 MiB,    128 MiB)   [16384][2048] bf16 (shared mids; tk overlay)
  //   hm_r    [60 MiB,   ~125.3 MiB) [RCAP][1024] bf16 -- overlaps w2t_sh+hm_sh,
  //           both dead once routed gemm1 launches (stream-ordered)
  //   g       [128 MiB,   +256 B)
  //   asg     [.., +131 KiB)
  char* ws = (char*)d_ws;
  short* xb     = (short*)(ws);
  short* w1t    = (short*)(ws + (size_t)33554432);
  short* w2t_r  = (short*)(ws + (size_t)50331648);
  short* w2t_sh = (short*)(ws + (size_t)62914560);
  short* hm_sh  = (short*)(ws + (size_t)67108864);
  short* hm_r   = (short*)(ws + (size_t)62914560);  // capacity 34816 rows >= 33408 worst
  int2*  tk     = (int2*)hm_sh;                     // consumed before gemms write hm
  int*   g      = (int*)(ws + (size_t)134217728);
  int*   asg    = (int*)(ws + (size_t)134217984);   // RCAP*4

  hipMemsetAsync(g, 0, 64, stream);
  hipMemsetAsync(asg, 0xFF, RCAP * sizeof(int), stream);

  cvt_x_k<<<8192, 256, 0, stream>>>(x, xb);
  transpose_k<<<dim3(16, 16, 16), 256, 0, stream>>>(sw1, rw1, sw2, rw2, w1t, w2t_sh, w2t_r);
  logits_k<<<4096, 256, 0, stream>>>(x, router_w, router_b, tk);
  hist_k<<<64, 256, 0, stream>>>(tk, g);
  prefix_k<<<1, 64, 0, stream>>>(g);
  scatter_k<<<64, 256, 0, stream>>>(tk, g, asg);

  // shared experts, K-merged: GEMM1 N=2048 -> hm_sh[16384][2048]; GEMM2 K=2048 -> out
  gemm1_k<0><<<dim3(128, 16), 256, 0, stream>>>(xb, H, w1t, H, H, sb1, hm_sh, 2048,
                                                nullptr, nullptr, 1 << 30);
  gemm2_k<0><<<dim3(128, 8), 256, 0, stream>>>(hm_sh, 2048, w2t_sh, 2048, 2048,
                                               sb2, sb2 + H, out, nullptr, nullptr, 1 << 30);

  // routed experts, batched single dispatches over padded compacted slots
  gemm1_k<1><<<dim3(RTILES, 8), 256, 0, stream>>>(xb, H, w1t + (size_t)2 * H * H, H, H,
                                                  rb1, hm_r, H, asg, g, RCAP);
  gemm2_k<3><<<dim3(RTILES, 8), 256, 0, stream>>>(hm_r, H, w2t_r, H, H,
                                                  rb2, nullptr, out, asg, g, RCAP);
}